// Round 5
// baseline (118.745 us; speedup 1.0000x reference)
//
#include <hip/hip_runtime.h>

#define NN 8192      // nodes (2 * batch)
#define NEDGE 524288 // total ragged neighbors
#define EMB 128
#define EPB 512      // edges per aggregation block

typedef __attribute__((ext_vector_type(8))) short bf16x8;
typedef __attribute__((ext_vector_type(4))) float f32x4;

__device__ __forceinline__ ushort f2bf(float f) {
    union { float f; uint u; } v; v.f = f;
    return (ushort)((v.u + 0x7FFF + ((v.u >> 16) & 1)) >> 16);  // RNE
}

__device__ __forceinline__ void flushAcc(float* __restrict__ Acc, int node, int c,
                                         const float4& ae, const float4& ar) {
    float* p = Acc + (size_t)node * 256 + c;
    atomicAdd(p + 0, ae.x); atomicAdd(p + 1, ae.y);
    atomicAdd(p + 2, ae.z); atomicAdd(p + 3, ae.w);
    float* q = p + 128;
    atomicAdd(q + 0, ar.x); atomicAdd(q + 1, ar.y);
    atomicAdd(q + 2, ar.z); atomicAdd(q + 3, ar.w);
}

// ---------------------------------------------------------------------------
// K0: weight prep (bf16 convert, native [n][k] layout).
// ---------------------------------------------------------------------------
__global__ __launch_bounds__(256) void k_prep(
    const float* __restrict__ Wt,   // [256][128]
    const float* __restrict__ Wn,   // [256][256]
    const float* __restrict__ bt,
    const float* __restrict__ bn,
    const float* __restrict__ Wr,   // [256][512]
    ushort* __restrict__ Wb1,       // [256][384] bf16
    float* __restrict__ bias1,      // [256]
    ushort* __restrict__ Wb2)       // [256][512] bf16
{
    const int j = blockIdx.x;    // 0..255
    const int t = threadIdx.x;
    for (int c = t; c < 384; c += 256) {
        const float v = (c < 128) ? Wt[(size_t)j * 128 + c]
                                  : Wn[(size_t)j * 256 + (c - 128)];
        Wb1[(size_t)j * 384 + c] = f2bf(v);
    }
    for (int c = t; c < 512; c += 256)
        Wb2[(size_t)j * 512 + c] = f2bf(Wr[(size_t)j * 512 + c]);
    if (t == 0) bias1[j] = bt[j] + bn[j];
}

// ---------------------------------------------------------------------------
// K1: flat edge-chunk aggregation with f32 atomic accumulation.
// 1024 blocks x 512 consecutive edges (uniform work, no ragged tail).
// Block: stage 512 edge index pairs in LDS, one binary search for the first
// node; 8 groups x 32 lanes each own 64 consecutive edges: 8-deep unrolled
// gathers (16 x 512B rows in flight), uniform scalar node-cursor detects
// segment boundaries and flushes partial sums via atomicAdd into Acc.
// ---------------------------------------------------------------------------
__global__ __launch_bounds__(256) void k_agg(
    const int* __restrict__ nbr_ent,
    const int* __restrict__ nbr_rel,
    const int* __restrict__ offsets,
    const float* __restrict__ ent_emb,
    const float* __restrict__ rel_emb,
    float* __restrict__ Acc)            // [NN][256] f32, pre-zeroed
{
    __shared__ int sie[EPB];
    __shared__ int sir[EPB];
    __shared__ int sNode0;

    const int b0 = blockIdx.x * EPB;
    const int t  = threadIdx.x;

    for (int i = t; i < EPB; i += 256) {
        sie[i] = nbr_ent[b0 + i];
        sir[i] = nbr_rel[b0 + i];
    }
    if (t == 0) {
        int lo = 0, hi = NN - 1;                 // largest node: offsets[node] <= b0
        while (lo < hi) {
            const int mid = (lo + hi + 1) >> 1;
            if (offsets[mid] <= b0) lo = mid; else hi = mid - 1;
        }
        sNode0 = lo;
    }
    __syncthreads();

    const int g     = t >> 5;            // 0..7
    const int lane  = t & 31;
    const int c     = lane * 4;
    const int gBase = g * 64;            // group's local edge base
    const int e0    = b0 + gBase;

    // advance uniform node cursor to this group's first edge
    int node = sNode0;
    int nodeEnd = (node + 1 < NN) ? offsets[node + 1] : NEDGE;
    while (nodeEnd <= e0) {
        ++node;
        nodeEnd = (node + 1 < NN) ? offsets[node + 1] : NEDGE;
    }

    float4 ae = make_float4(0.f, 0.f, 0.f, 0.f);
    float4 ar = make_float4(0.f, 0.f, 0.f, 0.f);

    for (int s = 0; s < 64; s += 8) {
        float4 ve0, ve1, ve2, ve3, ve4, ve5, ve6, ve7;
        float4 vr0, vr1, vr2, vr3, vr4, vr5, vr6, vr7;
        const int* ep = sie + gBase + s;
        const int* rp = sir + gBase + s;
        ve0 = *(const float4*)(ent_emb + (size_t)ep[0] * EMB + c);
        ve1 = *(const float4*)(ent_emb + (size_t)ep[1] * EMB + c);
        ve2 = *(const float4*)(ent_emb + (size_t)ep[2] * EMB + c);
        ve3 = *(const float4*)(ent_emb + (size_t)ep[3] * EMB + c);
        ve4 = *(const float4*)(ent_emb + (size_t)ep[4] * EMB + c);
        ve5 = *(const float4*)(ent_emb + (size_t)ep[5] * EMB + c);
        ve6 = *(const float4*)(ent_emb + (size_t)ep[6] * EMB + c);
        ve7 = *(const float4*)(ent_emb + (size_t)ep[7] * EMB + c);
        vr0 = *(const float4*)(rel_emb + (size_t)rp[0] * EMB + c);
        vr1 = *(const float4*)(rel_emb + (size_t)rp[1] * EMB + c);
        vr2 = *(const float4*)(rel_emb + (size_t)rp[2] * EMB + c);
        vr3 = *(const float4*)(rel_emb + (size_t)rp[3] * EMB + c);
        vr4 = *(const float4*)(rel_emb + (size_t)rp[4] * EMB + c);
        vr5 = *(const float4*)(rel_emb + (size_t)rp[5] * EMB + c);
        vr6 = *(const float4*)(rel_emb + (size_t)rp[6] * EMB + c);
        vr7 = *(const float4*)(rel_emb + (size_t)rp[7] * EMB + c);

        #pragma unroll
        for (int j = 0; j < 8; ++j) {
            const int e = e0 + s + j;
            if (e == nodeEnd) {                       // uniform branch
                flushAcc(Acc, node, c, ae, ar);
                ae = make_float4(0.f, 0.f, 0.f, 0.f);
                ar = make_float4(0.f, 0.f, 0.f, 0.f);
                ++node;
                nodeEnd = (node + 1 < NN) ? offsets[node + 1] : NEDGE;
                while (nodeEnd <= e) {                // skip empty nodes
                    ++node;
                    nodeEnd = (node + 1 < NN) ? offsets[node + 1] : NEDGE;
                }
            }
            const float4 ve = (j == 0) ? ve0 : (j == 1) ? ve1 : (j == 2) ? ve2 :
                              (j == 3) ? ve3 : (j == 4) ? ve4 : (j == 5) ? ve5 :
                              (j == 6) ? ve6 : ve7;
            const float4 vr = (j == 0) ? vr0 : (j == 1) ? vr1 : (j == 2) ? vr2 :
                              (j == 3) ? vr3 : (j == 4) ? vr4 : (j == 5) ? vr5 :
                              (j == 6) ? vr6 : vr7;
            ae.x += ve.x; ae.y += ve.y; ae.z += ve.z; ae.w += ve.w;
            ar.x += vr.x; ar.y += vr.y; ar.z += vr.z; ar.w += vr.w;
        }
    }
    flushAcc(Acc, node, c, ae, ar);      // final partial
}

// ---------------------------------------------------------------------------
// K1b: normalize + bf16 convert + fused self-entity gather.
// One 64-lane wave per node (4 nodes / 256-thr block).
//   Xcat[node] = bf16[ ent_row(128) | ne_mean(128) | nr_mean(128) ]
// ---------------------------------------------------------------------------
__global__ __launch_bounds__(256) void k_norm(
    const int* __restrict__ entities,
    const int* __restrict__ offsets,
    const float* __restrict__ ent_emb,
    const float* __restrict__ Acc,      // [NN][256] f32
    ushort* __restrict__ Xcat)          // [NN][384] bf16
{
    const int w    = threadIdx.x >> 6;
    const int lane = threadIdx.x & 63;
    const int node = blockIdx.x * 4 + w;
    const int start = offsets[node];
    const int end   = (node + 1 < NN) ? offsets[node + 1] : NEDGE;
    const int cnt   = end - start;
    const float inv = 1.0f / (float)(cnt > 1 ? cnt : 1);

    const float* arow = Acc + (size_t)node * 256;
    const float2 ne = *(const float2*)(arow + lane * 2);
    const float2 nr = *(const float2*)(arow + 128 + lane * 2);
    const float2 sv = *(const float2*)(ent_emb + (size_t)entities[node] * EMB + lane * 2);

    ushort* xrow = Xcat + (size_t)node * 384;
    ushort2 u;
    u.x = f2bf(sv.x);       u.y = f2bf(sv.y);       *(ushort2*)(xrow + lane * 2)       = u;
    u.x = f2bf(ne.x * inv); u.y = f2bf(ne.y * inv); *(ushort2*)(xrow + 128 + lane * 2) = u;
    u.x = f2bf(nr.x * inv); u.y = f2bf(nr.y * inv); *(ushort2*)(xrow + 256 + lane * 2) = u;
}

// ---------------------------------------------------------------------------
// K2: h = relu(Xcat @ Wb1^T + bias1), bf16 MFMA 16x16x32, f32 accum.
// Wave tile 16(M) x 64(N); block = 4 waves in M -> 64x64 tile.
// ---------------------------------------------------------------------------
__global__ __launch_bounds__(256) void k_gemm1(
    const ushort* __restrict__ A,     // [NN][384] bf16
    const ushort* __restrict__ B,     // [256][384] bf16
    const float* __restrict__ bias,   // [256]
    ushort* __restrict__ H)           // [NN][256] bf16
{
    const int wave = threadIdx.x >> 6;
    const int lane = threadIdx.x & 63;
    const int m0 = blockIdx.x * 64 + wave * 16;
    const int n0 = blockIdx.y * 64;
    const int lm = lane & 15;
    const int lk = (lane >> 4) * 8;

    const ushort* Ap  = A + (size_t)(m0 + lm) * 384 + lk;
    const ushort* Bp0 = B + (size_t)(n0 +  0 + lm) * 384 + lk;
    const ushort* Bp1 = B + (size_t)(n0 + 16 + lm) * 384 + lk;
    const ushort* Bp2 = B + (size_t)(n0 + 32 + lm) * 384 + lk;
    const ushort* Bp3 = B + (size_t)(n0 + 48 + lm) * 384 + lk;

    f32x4 acc0 = {0.f, 0.f, 0.f, 0.f};
    f32x4 acc1 = {0.f, 0.f, 0.f, 0.f};
    f32x4 acc2 = {0.f, 0.f, 0.f, 0.f};
    f32x4 acc3 = {0.f, 0.f, 0.f, 0.f};

    #pragma unroll
    for (int kb = 0; kb < 12; ++kb) {
        const bf16x8 a  = *(const bf16x8*)(Ap  + kb * 32);
        const bf16x8 b0 = *(const bf16x8*)(Bp0 + kb * 32);
        const bf16x8 b1 = *(const bf16x8*)(Bp1 + kb * 32);
        const bf16x8 b2 = *(const bf16x8*)(Bp2 + kb * 32);
        const bf16x8 b3 = *(const bf16x8*)(Bp3 + kb * 32);
        acc0 = __builtin_amdgcn_mfma_f32_16x16x32_bf16(a, b0, acc0, 0, 0, 0);
        acc1 = __builtin_amdgcn_mfma_f32_16x16x32_bf16(a, b1, acc1, 0, 0, 0);
        acc2 = __builtin_amdgcn_mfma_f32_16x16x32_bf16(a, b2, acc2, 0, 0, 0);
        acc3 = __builtin_amdgcn_mfma_f32_16x16x32_bf16(a, b3, acc3, 0, 0, 0);
    }

    const int r0 = (lane >> 4) * 4;
    f32x4 accs[4] = {acc0, acc1, acc2, acc3};
    #pragma unroll
    for (int ni = 0; ni < 4; ++ni) {
        const int col = n0 + ni * 16 + lm;
        const float bv = bias[col];
        #pragma unroll
        for (int j = 0; j < 4; ++j) {
            const int row = m0 + r0 + j;
            const float v = fmaxf(accs[ni][j] + bv, 0.f);
            H[(size_t)row * 256 + col] = f2bf(v);
        }
    }
}

// ---------------------------------------------------------------------------
// K3: pair = relu(H2 @ Wb2^T + b_r), H2 = H viewed [NN/2][512].
// ---------------------------------------------------------------------------
__global__ __launch_bounds__(256) void k_gemm2(
    const ushort* __restrict__ A,     // [NN/2][512] bf16
    const ushort* __restrict__ B,     // [256][512] bf16
    const float* __restrict__ bias,   // [256]
    float* __restrict__ out)          // [NN/2][256] f32
{
    const int wave = threadIdx.x >> 6;
    const int lane = threadIdx.x & 63;
    const int m0 = blockIdx.x * 64 + wave * 16;
    const int n0 = blockIdx.y * 64;
    const int lm = lane & 15;
    const int lk = (lane >> 4) * 8;

    const ushort* Ap  = A + (size_t)(m0 + lm) * 512 + lk;
    const ushort* Bp0 = B + (size_t)(n0 +  0 + lm) * 512 + lk;
    const ushort* Bp1 = B + (size_t)(n0 + 16 + lm) * 512 + lk;
    const ushort* Bp2 = B + (size_t)(n0 + 32 + lm) * 512 + lk;
    const ushort* Bp3 = B + (size_t)(n0 + 48 + lm) * 512 + lk;

    f32x4 acc0 = {0.f, 0.f, 0.f, 0.f};
    f32x4 acc1 = {0.f, 0.f, 0.f, 0.f};
    f32x4 acc2 = {0.f, 0.f, 0.f, 0.f};
    f32x4 acc3 = {0.f, 0.f, 0.f, 0.f};

    #pragma unroll
    for (int kb = 0; kb < 16; ++kb) {
        const bf16x8 a  = *(const bf16x8*)(Ap  + kb * 32);
        const bf16x8 b0 = *(const bf16x8*)(Bp0 + kb * 32);
        const bf16x8 b1 = *(const bf16x8*)(Bp1 + kb * 32);
        const bf16x8 b2 = *(const bf16x8*)(Bp2 + kb * 32);
        const bf16x8 b3 = *(const bf16x8*)(Bp3 + kb * 32);
        acc0 = __builtin_amdgcn_mfma_f32_16x16x32_bf16(a, b0, acc0, 0, 0, 0);
        acc1 = __builtin_amdgcn_mfma_f32_16x16x32_bf16(a, b1, acc1, 0, 0, 0);
        acc2 = __builtin_amdgcn_mfma_f32_16x16x32_bf16(a, b2, acc2, 0, 0, 0);
        acc3 = __builtin_amdgcn_mfma_f32_16x16x32_bf16(a, b3, acc3, 0, 0, 0);
    }

    const int r0 = (lane >> 4) * 4;
    f32x4 accs[4] = {acc0, acc1, acc2, acc3};
    #pragma unroll
    for (int ni = 0; ni < 4; ++ni) {
        const int col = n0 + ni * 16 + lm;
        const float bv = bias[col];
        #pragma unroll
        for (int j = 0; j < 4; ++j) {
            const int row = m0 + r0 + j;
            out[(size_t)row * 256 + col] = fmaxf(accs[ni][j] + bv, 0.f);
        }
    }
}

// ---------------------------------------------------------------------------
extern "C" void kernel_launch(void* const* d_in, const int* in_sizes, int n_in,
                              void* d_out, int out_size, void* d_ws, size_t ws_size,
                              hipStream_t stream) {
    const int*   entities = (const int*)d_in[0];
    const int*   nbr_ent  = (const int*)d_in[1];
    const int*   nbr_rel  = (const int*)d_in[2];
    const int*   offsets  = (const int*)d_in[3];
    const float* ent_emb  = (const float*)d_in[4];
    const float* rel_emb  = (const float*)d_in[5];
    const float* W_t      = (const float*)d_in[6];
    const float* b_t      = (const float*)d_in[7];
    const float* W_n      = (const float*)d_in[8];
    const float* b_n      = (const float*)d_in[9];
    const float* W_r      = (const float*)d_in[10];
    const float* b_r      = (const float*)d_in[11];
    float* out = (float*)d_out;

    char* ws = (char*)d_ws;
    // Acc (8 MB, f32) is dead after k_norm; H (4 MB) reuses its space.
    float*  Acc   = (float*)(ws);                   // [NN][256] f32 = 8388608 B
    ushort* H     = (ushort*)(ws);                  // [NN][256] bf16 = 4194304 B (after Acc dead)
    ushort* Xcat  = (ushort*)(ws + 8388608);        // [NN][384] bf16 = 6291456 B
    ushort* Wb1   = (ushort*)(ws + 14680064);       // 196608 B
    ushort* Wb2   = (ushort*)(ws + 14876672);       // 262144 B
    float*  bias1 = (float*)(ws + 15138816);        // 1024 B

    hipMemsetAsync(Acc, 0, (size_t)NN * 256 * sizeof(float), stream);
    hipLaunchKernelGGL(k_prep, dim3(256), dim3(256), 0, stream,
                       W_t, W_n, b_t, b_n, W_r, Wb1, bias1, Wb2);
    hipLaunchKernelGGL(k_agg, dim3(NEDGE / EPB), dim3(256), 0, stream,
                       nbr_ent, nbr_rel, offsets, ent_emb, rel_emb, Acc);
    hipLaunchKernelGGL(k_norm, dim3(NN / 4), dim3(256), 0, stream,
                       entities, offsets, ent_emb, Acc, Xcat);
    hipLaunchKernelGGL(k_gemm1, dim3(NN / 64, 4), dim3(256), 0, stream,
                       Xcat, Wb1, bias1, H);
    hipLaunchKernelGGL(k_gemm2, dim3(NN / 2 / 64, 4), dim3(256), 0, stream,
                       H, Wb2, b_r, out);
}

// Round 6
// 77.549 us; speedup vs baseline: 1.5312x; 1.5312x over previous
//
#include <hip/hip_runtime.h>

#define NN 8192      // nodes (2 * batch)
#define NEDGE 524288 // total ragged neighbors
#define EMB 128
#define TILE 512     // edge-index LDS tile

typedef __attribute__((ext_vector_type(8))) short bf16x8;
typedef __attribute__((ext_vector_type(4))) float f32x4;

__device__ __forceinline__ ushort f2bf(float f) {
    union { float f; uint u; } v; v.f = f;
    return (ushort)((v.u + 0x7FFF + ((v.u >> 16) & 1)) >> 16);  // RNE
}

// ---------------------------------------------------------------------------
// K1: fused prep + ragged aggregation (R4 structure, 8-deep unroll).
//  blocks [0,NN): one block per node, 256 threads = 8 groups x 32 lanes.
//    Stage 1: edge indices -> LDS (coalesced; kills idx->gather dep chain).
//    Stage 2: groups stride 64 over LDS indices, 8-way branchless unroll
//             (clamped idx + 0/1 FMA weight) -> 16 outstanding 16B gathers.
//    Output: Xcat[node] = bf16[ ent_row(128) | ne_mean(128) | nr_mean(128) ]
//  blocks [NN,NN+256): weight prep (bf16 convert, native [n][k] layout).
// ---------------------------------------------------------------------------
__global__ __launch_bounds__(256) void k_agg_prep(
    const int* __restrict__ entities,
    const int* __restrict__ nbr_ent,
    const int* __restrict__ nbr_rel,
    const int* __restrict__ offsets,
    const float* __restrict__ ent_emb,
    const float* __restrict__ rel_emb,
    const float* __restrict__ Wt,   // [256][128]
    const float* __restrict__ Wn,   // [256][256]
    const float* __restrict__ bt,
    const float* __restrict__ bn,
    const float* __restrict__ Wr,   // [256][512]
    ushort* __restrict__ Xcat,      // [NN][384] bf16
    ushort* __restrict__ Wb1,       // [256][384] bf16
    float* __restrict__ bias1,      // [256]
    ushort* __restrict__ Wb2)       // [256][512] bf16
{
    const int blk = blockIdx.x;
    if (blk >= NN) {                      // ---- weight-prep blocks ----
        const int j = blk - NN;           // 0..255
        const int t = threadIdx.x;
        for (int c = t; c < 384; c += 256) {
            const float v = (c < 128) ? Wt[(size_t)j * 128 + c]
                                      : Wn[(size_t)j * 256 + (c - 128)];
            Wb1[(size_t)j * 384 + c] = f2bf(v);
        }
        for (int c = t; c < 512; c += 256)
            Wb2[(size_t)j * 512 + c] = f2bf(Wr[(size_t)j * 512 + c]);
        if (t == 0) bias1[j] = bt[j] + bn[j];
        return;
    }

    // ---- aggregation blocks ----
    const int node  = blk;
    const int start = offsets[node];
    const int end   = (node + 1 < NN) ? offsets[node + 1] : NEDGE;
    const int cnt   = end - start;

    const int g    = threadIdx.x >> 5;   // 0..7
    const int lane = threadIdx.x & 31;   // 0..31
    const int c    = lane * 4;

    __shared__ int   sie[TILE];
    __shared__ int   sir[TILE];
    __shared__ float se[8][32][4];
    __shared__ float sr[8][32][4];

    float4 ae = make_float4(0.f, 0.f, 0.f, 0.f);
    float4 ar = make_float4(0.f, 0.f, 0.f, 0.f);

    for (int tb = start; tb < end; tb += TILE) {
        const int n = min(end - tb, TILE);
        __syncthreads();                                   // sie reusable
        for (int i = threadIdx.x; i < n; i += 256) {
            sie[i] = nbr_ent[tb + i];
            sir[i] = nbr_rel[tb + i];
        }
        __syncthreads();

        for (int i = g; i < n; i += 64) {
            // slots i + 8j, j=0..7 — branchless, all 16 loads always issued
            int   idx[8];
            float msk[8];
            #pragma unroll
            for (int j = 0; j < 8; ++j) {
                const int v = (j == 0) ? 1 : (i + 8 * j < n);
                idx[j] = v ? (i + 8 * j) : i;
                msk[j] = (float)v;
            }
            float4 ve[8], vr[8];
            #pragma unroll
            for (int j = 0; j < 8; ++j)
                ve[j] = *(const float4*)(ent_emb + (size_t)sie[idx[j]] * EMB + c);
            #pragma unroll
            for (int j = 0; j < 8; ++j)
                vr[j] = *(const float4*)(rel_emb + (size_t)sir[idx[j]] * EMB + c);
            #pragma unroll
            for (int j = 0; j < 8; ++j) {
                ae.x = fmaf(msk[j], ve[j].x, ae.x);
                ae.y = fmaf(msk[j], ve[j].y, ae.y);
                ae.z = fmaf(msk[j], ve[j].z, ae.z);
                ae.w = fmaf(msk[j], ve[j].w, ae.w);
                ar.x = fmaf(msk[j], vr[j].x, ar.x);
                ar.y = fmaf(msk[j], vr[j].y, ar.y);
                ar.z = fmaf(msk[j], vr[j].z, ar.z);
                ar.w = fmaf(msk[j], vr[j].w, ar.w);
            }
        }
    }

    se[g][lane][0] = ae.x; se[g][lane][1] = ae.y;
    se[g][lane][2] = ae.z; se[g][lane][3] = ae.w;
    sr[g][lane][0] = ar.x; sr[g][lane][1] = ar.y;
    sr[g][lane][2] = ar.z; sr[g][lane][3] = ar.w;
    __syncthreads();

    ushort* xrow = Xcat + (size_t)node * 384;
    if (threadIdx.x < 32) {
        const int l = threadIdx.x;
        float4 te = make_float4(0.f, 0.f, 0.f, 0.f);
        float4 tr = make_float4(0.f, 0.f, 0.f, 0.f);
        #pragma unroll
        for (int o = 0; o < 8; ++o) {
            te.x += se[o][l][0]; te.y += se[o][l][1];
            te.z += se[o][l][2]; te.w += se[o][l][3];
            tr.x += sr[o][l][0]; tr.y += sr[o][l][1];
            tr.z += sr[o][l][2]; tr.w += sr[o][l][3];
        }
        const float inv = 1.0f / (float)(cnt > 1 ? cnt : 1);
        ushort4 ue, ur;
        ue.x = f2bf(te.x * inv); ue.y = f2bf(te.y * inv);
        ue.z = f2bf(te.z * inv); ue.w = f2bf(te.w * inv);
        ur.x = f2bf(tr.x * inv); ur.y = f2bf(tr.y * inv);
        ur.z = f2bf(tr.z * inv); ur.w = f2bf(tr.w * inv);
        *(ushort4*)(xrow + 128 + l * 4) = ue;
        *(ushort4*)(xrow + 256 + l * 4) = ur;
    } else if (threadIdx.x < 64) {
        const int l  = threadIdx.x - 32;
        const int c2 = l * 4;
        const int ent = entities[node];
        const float4 v = *(const float4*)(ent_emb + (size_t)ent * EMB + c2);
        ushort4 u;
        u.x = f2bf(v.x); u.y = f2bf(v.y); u.z = f2bf(v.z); u.w = f2bf(v.w);
        *(ushort4*)(xrow + c2) = u;
    }
}

// ---------------------------------------------------------------------------
// K2: h = relu(Xcat @ Wb1^T + bias1), bf16 MFMA 16x16x32, f32 accum.
// Wave tile 16(M) x 64(N); block = 4 waves in M -> 64x64 tile.
// A/B frags: lane (m|n = l&15, k-octet = l>>4) -> 16B contiguous [row][k].
// C/D: col=l&15, row=(l>>4)*4+reg  [guide-verified m89/m91].
// ---------------------------------------------------------------------------
__global__ __launch_bounds__(256) void k_gemm1(
    const ushort* __restrict__ A,     // [NN][384] bf16
    const ushort* __restrict__ B,     // [256][384] bf16
    const float* __restrict__ bias,   // [256]
    ushort* __restrict__ H)           // [NN][256] bf16
{
    const int wave = threadIdx.x >> 6;
    const int lane = threadIdx.x & 63;
    const int m0 = blockIdx.x * 64 + wave * 16;
    const int n0 = blockIdx.y * 64;
    const int lm = lane & 15;
    const int lk = (lane >> 4) * 8;

    const ushort* Ap  = A + (size_t)(m0 + lm) * 384 + lk;
    const ushort* Bp0 = B + (size_t)(n0 +  0 + lm) * 384 + lk;
    const ushort* Bp1 = B + (size_t)(n0 + 16 + lm) * 384 + lk;
    const ushort* Bp2 = B + (size_t)(n0 + 32 + lm) * 384 + lk;
    const ushort* Bp3 = B + (size_t)(n0 + 48 + lm) * 384 + lk;

    f32x4 acc0 = {0.f, 0.f, 0.f, 0.f};
    f32x4 acc1 = {0.f, 0.f, 0.f, 0.f};
    f32x4 acc2 = {0.f, 0.f, 0.f, 0.f};
    f32x4 acc3 = {0.f, 0.f, 0.f, 0.f};

    #pragma unroll
    for (int kb = 0; kb < 12; ++kb) {
        const bf16x8 a  = *(const bf16x8*)(Ap  + kb * 32);
        const bf16x8 b0 = *(const bf16x8*)(Bp0 + kb * 32);
        const bf16x8 b1 = *(const bf16x8*)(Bp1 + kb * 32);
        const bf16x8 b2 = *(const bf16x8*)(Bp2 + kb * 32);
        const bf16x8 b3 = *(const bf16x8*)(Bp3 + kb * 32);
        acc0 = __builtin_amdgcn_mfma_f32_16x16x32_bf16(a, b0, acc0, 0, 0, 0);
        acc1 = __builtin_amdgcn_mfma_f32_16x16x32_bf16(a, b1, acc1, 0, 0, 0);
        acc2 = __builtin_amdgcn_mfma_f32_16x16x32_bf16(a, b2, acc2, 0, 0, 0);
        acc3 = __builtin_amdgcn_mfma_f32_16x16x32_bf16(a, b3, acc3, 0, 0, 0);
    }

    const int r0 = (lane >> 4) * 4;
    f32x4 accs[4] = {acc0, acc1, acc2, acc3};
    #pragma unroll
    for (int ni = 0; ni < 4; ++ni) {
        const int col = n0 + ni * 16 + lm;
        const float bv = bias[col];
        #pragma unroll
        for (int j = 0; j < 4; ++j) {
            const int row = m0 + r0 + j;
            const float v = fmaxf(accs[ni][j] + bv, 0.f);
            H[(size_t)row * 256 + col] = f2bf(v);
        }
    }
}

// ---------------------------------------------------------------------------
// K3: pair = relu(H2 @ Wb2^T + b_r), H2 = H viewed [NN/2][512].
// ---------------------------------------------------------------------------
__global__ __launch_bounds__(256) void k_gemm2(
    const ushort* __restrict__ A,     // [NN/2][512] bf16
    const ushort* __restrict__ B,     // [256][512] bf16
    const float* __restrict__ bias,   // [256]
    float* __restrict__ out)          // [NN/2][256] f32
{
    const int wave = threadIdx.x >> 6;
    const int lane = threadIdx.x & 63;
    const int m0 = blockIdx.x * 64 + wave * 16;
    const int n0 = blockIdx.y * 64;
    const int lm = lane & 15;
    const int lk = (lane >> 4) * 8;

    const ushort* Ap  = A + (size_t)(m0 + lm) * 512 + lk;
    const ushort* Bp0 = B + (size_t)(n0 +  0 + lm) * 512 + lk;
    const ushort* Bp1 = B + (size_t)(n0 + 16 + lm) * 512 + lk;
    const ushort* Bp2 = B + (size_t)(n0 + 32 + lm) * 512 + lk;
    const ushort* Bp3 = B + (size_t)(n0 + 48 + lm) * 512 + lk;

    f32x4 acc0 = {0.f, 0.f, 0.f, 0.f};
    f32x4 acc1 = {0.f, 0.f, 0.f, 0.f};
    f32x4 acc2 = {0.f, 0.f, 0.f, 0.f};
    f32x4 acc3 = {0.f, 0.f, 0.f, 0.f};

    #pragma unroll
    for (int kb = 0; kb < 16; ++kb) {
        const bf16x8 a  = *(const bf16x8*)(Ap  + kb * 32);
        const bf16x8 b0 = *(const bf16x8*)(Bp0 + kb * 32);
        const bf16x8 b1 = *(const bf16x8*)(Bp1 + kb * 32);
        const bf16x8 b2 = *(const bf16x8*)(Bp2 + kb * 32);
        const bf16x8 b3 = *(const bf16x8*)(Bp3 + kb * 32);
        acc0 = __builtin_amdgcn_mfma_f32_16x16x32_bf16(a, b0, acc0, 0, 0, 0);
        acc1 = __builtin_amdgcn_mfma_f32_16x16x32_bf16(a, b1, acc1, 0, 0, 0);
        acc2 = __builtin_amdgcn_mfma_f32_16x16x32_bf16(a, b2, acc2, 0, 0, 0);
        acc3 = __builtin_amdgcn_mfma_f32_16x16x32_bf16(a, b3, acc3, 0, 0, 0);
    }

    const int r0 = (lane >> 4) * 4;
    f32x4 accs[4] = {acc0, acc1, acc2, acc3};
    #pragma unroll
    for (int ni = 0; ni < 4; ++ni) {
        const int col = n0 + ni * 16 + lm;
        const float bv = bias[col];
        #pragma unroll
        for (int j = 0; j < 4; ++j) {
            const int row = m0 + r0 + j;
            out[(size_t)row * 256 + col] = fmaxf(accs[ni][j] + bv, 0.f);
        }
    }
}

// ---------------------------------------------------------------------------
extern "C" void kernel_launch(void* const* d_in, const int* in_sizes, int n_in,
                              void* d_out, int out_size, void* d_ws, size_t ws_size,
                              hipStream_t stream) {
    const int*   entities = (const int*)d_in[0];
    const int*   nbr_ent  = (const int*)d_in[1];
    const int*   nbr_rel  = (const int*)d_in[2];
    const int*   offsets  = (const int*)d_in[3];
    const float* ent_emb  = (const float*)d_in[4];
    const float* rel_emb  = (const float*)d_in[5];
    const float* W_t      = (const float*)d_in[6];
    const float* b_t      = (const float*)d_in[7];
    const float* W_n      = (const float*)d_in[8];
    const float* b_n      = (const float*)d_in[9];
    const float* W_r      = (const float*)d_in[10];
    const float* b_r      = (const float*)d_in[11];
    float* out = (float*)d_out;

    char* ws = (char*)d_ws;
    ushort* Xcat  = (ushort*)(ws);                  // 8192*384*2 = 6291456
    ushort* H     = (ushort*)(ws + 6291456);        // 8192*256*2 = 4194304
    ushort* Wb1   = (ushort*)(ws + 10485760);       // 256*384*2  = 196608
    ushort* Wb2   = (ushort*)(ws + 10682368);       // 256*512*2  = 262144
    float*  bias1 = (float*)(ws + 10944512);        // 1024

    hipLaunchKernelGGL(k_agg_prep, dim3(NN + 256), dim3(256), 0, stream,
                       entities, nbr_ent, nbr_rel, offsets, ent_emb, rel_emb,
                       W_t, W_n, b_t, b_n, W_r, Xcat, Wb1, bias1, Wb2);
    hipLaunchKernelGGL(k_gemm1, dim3(NN / 64, 4), dim3(256), 0, stream,
                       Xcat, Wb1, bias1, H);
    hipLaunchKernelGGL(k_gemm2, dim3(NN / 2 / 64, 4), dim3(256), 0, stream,
                       H, Wb2, b_r, out);
}